// Round 5
// baseline (6962.406 us; speedup 1.0000x reference)
//
#include <hip/hip_runtime.h>
#include <cstdint>

// ---------------------------------------------------------------------------
// RNNres: emb -> LSTM(T=2048,B=64,NHID=256) -> ragged mean pool -> ResNet head
// Round-5 k2: three-pipe weight supply sized to measured bandwidths.
//   - 64 pairs/row in VGPRs (128 words; h2a side only -> static readlanes)
//   - 18 uint4 groups in LDS (pairs 64..99; ds_read_b128, 147KB/step)
//   - 14 uint2 groups streamed from L2 each step (pairs 100..127; 115KB shared
//     packed buffer, re-loaded per step)
//   LDS + stream addresses are rotated by t so LICM cannot hoist them out of
//   the 2048-step loop (r1-r4: hoisted loop-invariant reads blew pressure to
//   ~285 words -> allocator gave up at 128 VGPR + ~150-word scratch spill =
//   the 18.4MB WRITE_SIZE + 4700 cyc/step plateau).
//   Weight packing done once in k0b (reuses dead emb16 region after k1).
// ---------------------------------------------------------------------------

#define NTOKEN 50257
#define NINP 256
#define NHID 256
#define BB 64
#define TT 2048
#define NRES 10
#define NFC1 85
#define EPSV 1e-5f

typedef _Float16 f16;
typedef _Float16 f16x2 __attribute__((ext_vector_type(2)));
typedef _Float16 f16x8 __attribute__((ext_vector_type(8)));
typedef float f32x4 __attribute__((ext_vector_type(4)));

static __device__ __forceinline__ float sigm(float x) { return 1.0f / (1.0f + __expf(-x)); }
static __device__ __forceinline__ float tanh_(float x) {
  float ax = fabsf(x);
  float e = __expf(-2.0f * ax);
  float t = (1.0f - e) / (1.0f + e);
  return x < 0.0f ? -t : t;
}

static __device__ __forceinline__ float fdot2u(unsigned int a, unsigned int b, float c) {
#if __has_builtin(__builtin_amdgcn_fdot2)
  return __builtin_amdgcn_fdot2(__builtin_bit_cast(f16x2, a), __builtin_bit_cast(f16x2, b), c, false);
#else
  f16x2 av = __builtin_bit_cast(f16x2, a), bv = __builtin_bit_cast(f16x2, b);
  return c + (float)av[0] * (float)bv[0] + (float)av[1] * (float)bv[1];
#endif
}

// ---------------------------------------------------------------- k0: convert
__global__ void k0_convert(const float* __restrict__ emb_w, const float* __restrict__ W_ih,
                           const float* __restrict__ b_ih, const float* __restrict__ b_hh,
                           f16* __restrict__ emb16, f16* __restrict__ wih16,
                           float* __restrict__ bias) {
  int64_t i = (int64_t)blockIdx.x * blockDim.x + threadIdx.x;
  if (i < (int64_t)NTOKEN * NINP) emb16[i] = (f16)emb_w[i];
  if (i < 4 * NHID * NINP) wih16[i] = (f16)W_ih[i];
  if (i < 4 * NHID) bias[i] = b_ih[i] + b_hh[i];
}

// ------------------------------------------------- k1: gate-table f16 GEMM
__global__ __launch_bounds__(256) void k1_gemm(const f16* __restrict__ emb16,
                                               const f16* __restrict__ wih16,
                                               const float* __restrict__ bias,
                                               f16* __restrict__ xgtab) {
  __shared__ __align__(16) f16 a_lds[64][40];
  __shared__ __align__(16) f16 b_lds[256][40];
  const int mt = blockIdx.x;
  const int nt0 = blockIdx.y * 256;
  const int tid = threadIdx.x;
  const int lane = tid & 63;
  const int w = tid >> 6;
  const int quad = lane >> 4;
  const int l16 = lane & 15;

  f32x4 acc[16];
#pragma unroll
  for (int i = 0; i < 16; i++) acc[i] = (f32x4){0.f, 0.f, 0.f, 0.f};

  const int ar = tid >> 2;
  int av = mt * 64 + ar;
  if (av > NTOKEN - 1) av = NTOKEN - 1;
  const int ac = (tid & 3) * 8;

  for (int kb = 0; kb < 256; kb += 32) {
    *(uint4*)&a_lds[ar][ac] = *(const uint4*)&emb16[av * 256 + kb + ac];
    {
      const uint4* bs = (const uint4*)&wih16[(nt0 + tid) * 256 + kb];
      uint4* bd = (uint4*)&b_lds[tid][0];
      bd[0] = bs[0]; bd[1] = bs[1]; bd[2] = bs[2]; bd[3] = bs[3];
    }
    __syncthreads();
    f16x8 af = *(const f16x8*)&a_lds[w * 16 + l16][quad * 8];
#pragma unroll
    for (int nt = 0; nt < 16; nt++) {
      f16x8 bf = *(const f16x8*)&b_lds[nt * 16 + l16][quad * 8];
      acc[nt] = __builtin_amdgcn_mfma_f32_16x16x32_f16(af, bf, acc[nt], 0, 0, 0);
    }
    __syncthreads();
  }
#pragma unroll
  for (int nt = 0; nt < 16; nt++) {
#pragma unroll
    for (int rg = 0; rg < 4; rg++) {
      int v = mt * 64 + w * 16 + quad * 4 + rg;
      if (v < NTOKEN) {
        int n = nt0 + nt * 16 + l16;
        xgtab[v * 1024 + n] = (f16)(acc[nt][rg] + bias[n]);
      }
    }
  }
}

// --------------------------------------------- k0b: pack W_hh for k2's pipes
// wreg : pairs 0..63   -> uint  wreg[m*1024 + r]
// wlds : pairs 64..99  -> uint4 groups [q*512 + (r&511)], comps {w0,w1,w0',w1'}
// wstr : pairs 100..127-> uint2 groups [g*1024 + r] = {pair(100+2g), pair(101+2g)}
__global__ __launch_bounds__(128) void k0b_pack(const float* __restrict__ Whh,
                                                unsigned int* __restrict__ wreg,
                                                unsigned int* __restrict__ wlds,
                                                unsigned int* __restrict__ wstr) {
  const int r = blockIdx.x;        // row 0..1023
  const int j = threadIdx.x;       // pair 0..127
  float2 a = *(const float2*)&Whh[r * 256 + 2 * j];
  f16x2 p; p[0] = (f16)a.x; p[1] = (f16)a.y;
  unsigned int u = __builtin_bit_cast(unsigned int, p);
  if (j < 64) {
    wreg[j * 1024 + r] = u;
  } else if (j < 100) {
    int q = (j - 64) >> 1;
    wlds[(q * 512 + (r & 511)) * 4 + ((j & 1) * 2) + (r >> 9)] = u;
  } else {
    int g = (j - 100) >> 1;
    wstr[(g * 1024 + r) * 2 + (j & 1)] = u;
  }
}

// ------------------------------------------------------- k2: LSTM recurrence
// One WG per batch element, 512 thr (8 waves, 2/SIMD). Thread t owns gate rows
// r0=tid (i or f) and r1=tid+512 (g or o). h packed half2 per lane (h2a pairs
// 0..63, h2b pairs 64..127), broadcast via v_readlane.
#define RP 64   // pairs resident in VGPRs (m 0..63)
#define LQ 18   // LDS uint4 groups       (m 64..99)
#define SG 14   // stream uint2 groups    (m 100..127)
__global__ __launch_bounds__(512, 2) void k2_rnn(
    const int* __restrict__ input, const float* __restrict__ hx0,
    const float* __restrict__ cx0, const int* __restrict__ seq_len,
    const unsigned int* __restrict__ wreg, const uint4* __restrict__ wldsg,
    const uint2* __restrict__ wstr, const f16* __restrict__ xgtab,
    float* __restrict__ feat, float* __restrict__ out_hx, float* __restrict__ out_cx) {
  __shared__ uint4 lw4[LQ * 512];                 // 147456 B
  __shared__ __align__(8) f16 hpak[NHID];         // 512 B
  __shared__ float fo_f[NHID];
  __shared__ float fo_o[NHID];

  const int b = blockIdx.x;
  const int tid = threadIdx.x;
  const int lane = tid & 63;
  const int r0 = tid, r1 = tid + 512;

  // resident weights: pairs 0..63 for both rows (128 VGPRs)
  unsigned int w0[RP], w1[RP];
#pragma unroll
  for (int m = 0; m < RP; m++) {
    w0[m] = wreg[m * 1024 + tid];
    w1[m] = wreg[m * 1024 + 512 + tid];
  }
  // LDS-resident weights: pairs 64..99
#pragma unroll
  for (int q = 0; q < LQ; q++) lw4[q * 512 + tid] = wldsg[q * 512 + tid];

  float c = 0.0f, pool = 0.0f, hnew = 0.0f;
  if (tid < NHID) {
    hpak[tid] = (f16)hx0[b * NHID + tid];
    c = cx0[b * NHID + tid];
  }
  const int L = seq_len[b];
  __syncthreads();

  const unsigned int* hpu = (const unsigned int*)hpak;
  unsigned int h2a = hpu[lane];        // pairs 0..63   (lane = pair)
  unsigned int h2b = hpu[64 + lane];   // pairs 64..127 (lane = pair-64)

  const int* tokp = input + b * TT;
  int tok_next = __builtin_amdgcn_readfirstlane(tokp[1]);
  f16 xga, xgb;
  {
    int tok0 = __builtin_amdgcn_readfirstlane(tokp[0]);
    xga = xgtab[tok0 * 1024 + r0];
    xgb = xgtab[tok0 * 1024 + r1];
  }

  int toffL = 0, toffS = 0;   // rotation offsets (defeat LICM of LDS/stream reads)
#pragma unroll 1
  for (int t = 0; t < TT; t++) {
    // token + x-gate prefetch (L3/HBM gather, consumed at loop end)
    int tn = (t + 2 < TT) ? __builtin_amdgcn_readfirstlane(tokp[t + 2]) : 0;
    const f16* tp = xgtab + (size_t)tok_next * 1024;
    f16 pfa = tp[r0];
    f16 pfb = tp[r1];

    float a0l = (float)xga, a1l = (float)xgb;   // REG + streamA chains
    float a0h = 0.f, a1h = 0.f;                 // LDS + streamB chains

    // ---- stream batch A issue (groups 0..6 rotated)
    uint2 sA0[7], sA1[7]; int geA[7];
#pragma unroll
    for (int s = 0; s < 7; s++) {
      int ge = s + toffS; if (ge >= SG) ge -= SG;
      geA[s] = ge;
      sA0[s] = wstr[ge * 1024 + tid];
      sA1[s] = wstr[ge * 1024 + 512 + tid];
    }

    // ---- REG segment, first half (pairs 0..31)
#pragma unroll
    for (int m = 0; m < 32; m++) {
      unsigned int hs = (unsigned int)__builtin_amdgcn_readlane((int)h2a, m);
      a0l = fdot2u(w0[m], hs, a0l);
      a1l = fdot2u(w1[m], hs, a1l);
    }

    // ---- stream batch B issue (groups 7..13 rotated)
    uint2 sB0[7], sB1[7]; int geB[7];
#pragma unroll
    for (int s = 0; s < 7; s++) {
      int ge = s + 7 + toffS; if (ge >= SG) ge -= SG;
      geB[s] = ge;
      sB0[s] = wstr[ge * 1024 + tid];
      sB1[s] = wstr[ge * 1024 + 512 + tid];
    }

    // ---- REG segment, second half (pairs 32..63)
#pragma unroll
    for (int m = 32; m < RP; m++) {
      unsigned int hs = (unsigned int)__builtin_amdgcn_readlane((int)h2a, m);
      a0l = fdot2u(w0[m], hs, a0l);
      a1l = fdot2u(w1[m], hs, a1l);
    }

    // ---- consume stream A (pairs 100+2ge, 101+2ge)
#pragma unroll
    for (int s = 0; s < 7; s++) {
      int ge = geA[s];
      unsigned int hs0 = (unsigned int)__builtin_amdgcn_readlane((int)h2b, 36 + 2 * ge);
      unsigned int hs1 = (unsigned int)__builtin_amdgcn_readlane((int)h2b, 37 + 2 * ge);
      a0l = fdot2u(sA0[s].x, hs0, a0l);
      a1l = fdot2u(sA1[s].x, hs0, a1l);
      a0l = fdot2u(sA0[s].y, hs1, a0l);
      a1l = fdot2u(sA1[s].y, hs1, a1l);
    }

    // ---- LDS segment (pairs 64+2qe, 65+2qe), rotated
#pragma unroll
    for (int q = 0; q < LQ; q++) {
      int qe = q + toffL; if (qe >= LQ) qe -= LQ;
      uint4 w = lw4[qe * 512 + tid];
      unsigned int hs0 = (unsigned int)__builtin_amdgcn_readlane((int)h2b, 2 * qe);
      unsigned int hs1 = (unsigned int)__builtin_amdgcn_readlane((int)h2b, 2 * qe + 1);
      a0h = fdot2u(w.x, hs0, a0h);
      a1h = fdot2u(w.y, hs0, a1h);
      a0h = fdot2u(w.z, hs1, a0h);
      a1h = fdot2u(w.w, hs1, a1h);
    }

    // ---- consume stream B
#pragma unroll
    for (int s = 0; s < 7; s++) {
      int ge = geB[s];
      unsigned int hs0 = (unsigned int)__builtin_amdgcn_readlane((int)h2b, 36 + 2 * ge);
      unsigned int hs1 = (unsigned int)__builtin_amdgcn_readlane((int)h2b, 37 + 2 * ge);
      a0h = fdot2u(sB0[s].x, hs0, a0h);
      a1h = fdot2u(sB1[s].x, hs0, a1h);
      a0h = fdot2u(sB0[s].y, hs1, a0h);
      a1h = fdot2u(sB1[s].y, hs1, a1h);
    }

    float acc0 = a0l + a0h;
    float acc1 = a1l + a1h;

    // activations pre-barrier, balanced across all 8 waves
    float p = 0.f;
    if (tid >= NHID) {
      fo_f[tid - NHID] = sigm(acc0);
      fo_o[tid - NHID] = sigm(acc1);
    } else {
      p = sigm(acc0) * tanh_(acc1);    // i*g
    }
    __syncthreads();
    if (tid < NHID) {
      c = fo_f[tid] * c + p;
      hnew = fo_o[tid] * tanh_(c);
      pool += (t < L) ? hnew : 0.f;
      hpak[tid] = (f16)hnew;
    }
    __syncthreads();
    h2a = hpu[lane];
    h2b = hpu[64 + lane];
    xga = pfa; xgb = pfb; tok_next = tn;
    toffS++; if (toffS == SG) toffS = 0;
    toffL++; if (toffL == LQ) toffL = 0;
  }

  if (tid < NHID) {
    feat[b * NHID + tid] = pool / (float)L;
    out_hx[b * NHID + tid] = hnew;
    out_cx[b * NHID + tid] = c;
  }
}

// ------------------------------------------------------------- k3: head (fp32)
__global__ __launch_bounds__(256) void k3_head(const float* __restrict__ feat,
    const float* __restrict__ rfc1_w, const float* __restrict__ rfc1_b,
    const float* __restrict__ rbn_g, const float* __restrict__ rbn_b,
    const float* __restrict__ rbn_rm, const float* __restrict__ rbn_rv,
    const float* __restrict__ rfc2_w, const float* __restrict__ rfc2_b,
    const float* __restrict__ fc1_w, const float* __restrict__ fc1_b,
    const float* __restrict__ bn1_g, const float* __restrict__ bn1_b,
    const float* __restrict__ bn1_rm, const float* __restrict__ bn1_rv,
    const float* __restrict__ fc2_w, const float* __restrict__ fc2_b,
    float* __restrict__ logp) {
  __shared__ float f[256];
  __shared__ float f2[256];
  __shared__ float res[16];
  __shared__ float fcv[96];
  const int b = blockIdx.x, tid = threadIdx.x;
  const int wv = tid >> 6, lane = tid & 63;
  f[tid] = feat[b * 256 + tid];
  __syncthreads();
  for (int r = wv; r < NRES; r += 4) {
    float p = 0.f;
#pragma unroll
    for (int j0 = 0; j0 < 4; j0++) {
      int j = lane * 4 + j0;
      p += fmaxf(f[j], 0.f) * rfc1_w[r * 256 + j];
    }
    for (int off = 32; off > 0; off >>= 1) p += __shfl_down(p, off);
    if (lane == 0) {
      float x = p + rfc1_b[r];
      x = fmaxf(x, 0.f);
      x = (x - rbn_rm[r]) * rsqrtf(rbn_rv[r] + EPSV) * rbn_g[r] + rbn_b[r];
      res[r] = x;
    }
  }
  __syncthreads();
  {
    float s = rfc2_b[tid];
#pragma unroll
    for (int r = 0; r < NRES; r++) s += res[r] * rfc2_w[tid * NRES + r];
    f2[tid] = f[tid] + s;
  }
  __syncthreads();
  for (int o = wv; o < NFC1; o += 4) {
    float p = 0.f;
#pragma unroll
    for (int j0 = 0; j0 < 4; j0++) {
      int j = lane * 4 + j0;
      p += f2[j] * fc1_w[o * 256 + j];
    }
    for (int off = 32; off > 0; off >>= 1) p += __shfl_down(p, off);
    if (lane == 0) {
      float x = p + fc1_b[o];
      x = (x - bn1_rm[o]) * rsqrtf(bn1_rv[o] + EPSV) * bn1_g[o] + bn1_b[o];
      x = fmaxf(x, 0.01f * x);
      fcv[o] = x;
    }
  }
  __syncthreads();
  if (tid == 0) {
    float l0 = fc2_b[0], l1 = fc2_b[1];
    for (int o2 = 0; o2 < NFC1; o2++) {
      l0 += fcv[o2] * fc2_w[o2];
      l1 += fcv[o2] * fc2_w[NFC1 + o2];
    }
    float mx = fmaxf(l0, l1);
    float lse = mx + __logf(__expf(l0 - mx) + __expf(l1 - mx));
    logp[b * 2 + 0] = l0 - lse;
    logp[b * 2 + 1] = l1 - lse;
  }
}

// ---------------------------------------------------------------------------
extern "C" void kernel_launch(void* const* d_in, const int* in_sizes, int n_in,
                              void* d_out, int out_size, void* d_ws, size_t ws_size,
                              hipStream_t stream) {
  const int*   input  = (const int*)  d_in[0];
  const float* hx     = (const float*)d_in[1];
  const float* cx     = (const float*)d_in[2];
  const int*   seqlen = (const int*)  d_in[3];
  const float* emb_w  = (const float*)d_in[4];
  const float* W_ih   = (const float*)d_in[5];
  const float* W_hh   = (const float*)d_in[6];
  const float* b_ih   = (const float*)d_in[7];
  const float* b_hh   = (const float*)d_in[8];
  const float* rfc1_w = (const float*)d_in[9];
  const float* rfc1_b = (const float*)d_in[10];
  const float* rbn_g  = (const float*)d_in[11];
  const float* rbn_b  = (const float*)d_in[12];
  const float* rbn_rm = (const float*)d_in[13];
  const float* rbn_rv = (const float*)d_in[14];
  const float* rfc2_w = (const float*)d_in[15];
  const float* rfc2_b = (const float*)d_in[16];
  const float* fc1_w  = (const float*)d_in[17];
  const float* fc1_b  = (const float*)d_in[18];
  const float* bn1_g  = (const float*)d_in[19];
  const float* bn1_b  = (const float*)d_in[20];
  const float* bn1_rm = (const float*)d_in[21];
  const float* bn1_rv = (const float*)d_in[22];
  const float* fc2_w  = (const float*)d_in[23];
  const float* fc2_b  = (const float*)d_in[24];

  char* ws = (char*)d_ws;
  f16*   emb16 = (f16*)(ws);                 // 25,731,584 B (dead after k1)
  f16*   wih16 = (f16*)(ws + 25731584);      //    524,288 B
  float* bias  = (float*)(ws + 26255872);    //      4,096 B
  f16*   xgtab = (f16*)(ws + 26259968);      // 102,926,336 B
  float* feat  = (float*)(ws + 129186304);   //     65,536 B

  // packed W_hh buffers overlay the dead emb16 region (k0b runs after k1)
  unsigned int* wreg = (unsigned int*)(ws);            // 64*1024*4  = 262,144 B
  unsigned int* wlds = (unsigned int*)(ws + 262144);   // 18*512*16  = 147,456 B
  unsigned int* wstr = (unsigned int*)(ws + 409600);   // 14*1024*8  = 114,688 B

  float* out = (float*)d_out;   // [0,128): logp, [128,16512): hx_f, [16512,32896): cx_f

  k0_convert<<<dim3(NTOKEN), 256, 0, stream>>>(emb_w, W_ih, b_ih, b_hh, emb16, wih16, bias);
  k1_gemm<<<dim3((NTOKEN + 63) / 64, 4), 256, 0, stream>>>(emb16, wih16, bias, xgtab);
  k0b_pack<<<dim3(1024), 128, 0, stream>>>(W_hh, wreg, wlds, wstr);
  k2_rnn<<<dim3(BB), 512, 0, stream>>>(input, hx, cx, seqlen, wreg, (const uint4*)wlds,
                                       (const uint2*)wstr, xgtab, feat,
                                       out + 128, out + 128 + BB * NHID);
  k3_head<<<dim3(BB), 256, 0, stream>>>(feat, rfc1_w, rfc1_b, rbn_g, rbn_b, rbn_rm, rbn_rv,
                                        rfc2_w, rfc2_b, fc1_w, fc1_b, bn1_g, bn1_b, bn1_rm,
                                        bn1_rv, fc2_w, fc2_b, out);
}

// Round 6
// 4355.136 us; speedup vs baseline: 1.5987x; 1.5987x over previous
//
#include <hip/hip_runtime.h>
#include <cstdint>

// ---------------------------------------------------------------------------
// RNNres: emb -> LSTM(T=2048,B=64,NHID=256) -> ragged mean pool -> ResNet head
// Round-6 k2: designed TO the allocator's 128-VGPR point instead of against it.
//   1024 threads (16 waves, 4/SIMD = the 128-reg occupancy sweet spot).
//   Thread u: hidden unit r=u&255, K-quarter q=u>>8; owns gate rows
//   {r, r+256, r+512, r+768} = {i,f,g,o}[r] over h-pairs [32q,32q+32).
//   Weights: 23 uint4/thread in regs (92 words) + 9 uint4 via LDS (rotated
//   to defeat LICM). 1 readlane feeds 4 fdot2. q=0 thread combines the 4
//   quarter-partials (LDS float4) + x-gate and applies activations; c/pool
//   live in its registers. Demand ~122 regs <= 128 -> no spill, no remat
//   (r5 lesson: spills fixed but compiler rematerialized 128 words from L2
//   every step = 5700 cyc; r1-r4: 150-word scratch spill = 18MB WRITE_SIZE).
// ---------------------------------------------------------------------------

#define NTOKEN 50257
#define NINP 256
#define NHID 256
#define BB 64
#define TT 2048
#define NRES 10
#define NFC1 85
#define EPSV 1e-5f

#define QP 23   // reg-resident uint4 weight groups per thread (92 words)
#define LJ 9    // LDS-resident uint4 weight groups per thread (36 words)

typedef _Float16 f16;
typedef _Float16 f16x2 __attribute__((ext_vector_type(2)));
typedef _Float16 f16x8 __attribute__((ext_vector_type(8)));
typedef float f32x4 __attribute__((ext_vector_type(4)));

static __device__ __forceinline__ float sigm(float x) { return 1.0f / (1.0f + __expf(-x)); }
static __device__ __forceinline__ float tanh_(float x) {
  float ax = fabsf(x);
  float e = __expf(-2.0f * ax);
  float t = (1.0f - e) / (1.0f + e);
  return x < 0.0f ? -t : t;
}

static __device__ __forceinline__ float fdot2u(unsigned int a, unsigned int b, float c) {
#if __has_builtin(__builtin_amdgcn_fdot2)
  return __builtin_amdgcn_fdot2(__builtin_bit_cast(f16x2, a), __builtin_bit_cast(f16x2, b), c, false);
#else
  f16x2 av = __builtin_bit_cast(f16x2, a), bv = __builtin_bit_cast(f16x2, b);
  return c + (float)av[0] * (float)bv[0] + (float)av[1] * (float)bv[1];
#endif
}

// ---------------------------------------------------------------- k0: convert
__global__ void k0_convert(const float* __restrict__ emb_w, const float* __restrict__ W_ih,
                           const float* __restrict__ b_ih, const float* __restrict__ b_hh,
                           f16* __restrict__ emb16, f16* __restrict__ wih16,
                           float* __restrict__ bias) {
  int64_t i = (int64_t)blockIdx.x * blockDim.x + threadIdx.x;
  if (i < (int64_t)NTOKEN * NINP) emb16[i] = (f16)emb_w[i];
  if (i < 4 * NHID * NINP) wih16[i] = (f16)W_ih[i];
  if (i < 4 * NHID) bias[i] = b_ih[i] + b_hh[i];
}

// ------------------------------------------------- k1: gate-table f16 GEMM
__global__ __launch_bounds__(256) void k1_gemm(const f16* __restrict__ emb16,
                                               const f16* __restrict__ wih16,
                                               const float* __restrict__ bias,
                                               f16* __restrict__ xgtab) {
  __shared__ __align__(16) f16 a_lds[64][40];
  __shared__ __align__(16) f16 b_lds[256][40];
  const int mt = blockIdx.x;
  const int nt0 = blockIdx.y * 256;
  const int tid = threadIdx.x;
  const int lane = tid & 63;
  const int w = tid >> 6;
  const int quad = lane >> 4;
  const int l16 = lane & 15;

  f32x4 acc[16];
#pragma unroll
  for (int i = 0; i < 16; i++) acc[i] = (f32x4){0.f, 0.f, 0.f, 0.f};

  const int ar = tid >> 2;
  int av = mt * 64 + ar;
  if (av > NTOKEN - 1) av = NTOKEN - 1;
  const int ac = (tid & 3) * 8;

  for (int kb = 0; kb < 256; kb += 32) {
    *(uint4*)&a_lds[ar][ac] = *(const uint4*)&emb16[av * 256 + kb + ac];
    {
      const uint4* bs = (const uint4*)&wih16[(nt0 + tid) * 256 + kb];
      uint4* bd = (uint4*)&b_lds[tid][0];
      bd[0] = bs[0]; bd[1] = bs[1]; bd[2] = bs[2]; bd[3] = bs[3];
    }
    __syncthreads();
    f16x8 af = *(const f16x8*)&a_lds[w * 16 + l16][quad * 8];
#pragma unroll
    for (int nt = 0; nt < 16; nt++) {
      f16x8 bf = *(const f16x8*)&b_lds[nt * 16 + l16][quad * 8];
      acc[nt] = __builtin_amdgcn_mfma_f32_16x16x32_f16(af, bf, acc[nt], 0, 0, 0);
    }
    __syncthreads();
  }
#pragma unroll
  for (int nt = 0; nt < 16; nt++) {
#pragma unroll
    for (int rg = 0; rg < 4; rg++) {
      int v = mt * 64 + w * 16 + quad * 4 + rg;
      if (v < NTOKEN) {
        int n = nt0 + nt * 16 + l16;
        xgtab[v * 1024 + n] = (f16)(acc[nt][rg] + bias[n]);
      }
    }
  }
}

// --------------------------------------------- k0b: pack W_hh for k2
// For k2-thread u (r=u&255, q=u>>5 of pair... see k2): group pi holds pair
// p = 32*(u>>8) + pi for the 4 gate rows {r, r+256, r+512, r+768} as .x/.y/.z/.w.
__global__ __launch_bounds__(128) void k0b_pack(const float* __restrict__ Whh,
                                                unsigned int* __restrict__ wregq,
                                                unsigned int* __restrict__ wldsq) {
  const int R = blockIdx.x;        // gate row 0..1023
  const int p = threadIdx.x;       // pair 0..127
  float2 a = *(const float2*)&Whh[R * 256 + 2 * p];
  f16x2 pk; pk[0] = (f16)a.x; pk[1] = (f16)a.y;
  unsigned int uu = __builtin_bit_cast(unsigned int, pk);
  int u = (R & 255) + 256 * (p >> 5);   // k2 thread that consumes this pair
  int ri = R >> 8;                      // gate index (i,f,g,o)
  int pp = p & 31;                      // pair index within the quarter
  if (pp < QP) wregq[(pp * 1024 + u) * 4 + ri] = uu;
  else         wldsq[((pp - QP) * 1024 + u) * 4 + ri] = uu;
}

// ------------------------------------------------------- k2: LSTM recurrence
// One WG per batch element, 1024 thr (16 waves, 4/SIMD, 128-reg budget).
__global__ __launch_bounds__(1024) void k2_rnn(
    const int* __restrict__ input, const float* __restrict__ hx0,
    const float* __restrict__ cx0, const int* __restrict__ seq_len,
    const uint4* __restrict__ wregq, const uint4* __restrict__ wldsq,
    const f16* __restrict__ xgtab,
    float* __restrict__ feat, float* __restrict__ out_hx, float* __restrict__ out_cx) {
  __shared__ uint4 lw4[LJ * 1024];            // 147456 B
  __shared__ float part[3 * 256 * 4];         //  12288 B  (quarters 1..3 partials)
  __shared__ f16 xbuf[1024];                  //   2048 B  (current step x-gates)
  __shared__ __align__(8) f16 hpak[NHID];     //    512 B  -> total 162304 B

  const int b = blockIdx.x;
  const int u = threadIdx.x;
  const int lane = u & 63;
  const int r = u & 255;        // hidden unit
  const int q = u >> 8;         // K-quarter (wave-uniform)

  // resident weights: 23 uint4 (pairs 32q .. 32q+22, gates i,f,g,o)
  uint4 w4[QP];
#pragma unroll
  for (int i = 0; i < QP; i++) w4[i] = wregq[i * 1024 + u];
  // LDS weights: 9 uint4 (pairs 32q+23 .. 32q+31)
#pragma unroll
  for (int j = 0; j < LJ; j++) lw4[j * 1024 + u] = wldsq[j * 1024 + u];

  float c = 0.f, pool = 0.f, h = 0.f;
  if (u < NHID) {
    hpak[u] = (f16)hx0[b * NHID + u];
    c = cx0[b * NHID + u];
  }
  const int L = seq_len[b];
  const int* tokp = input + b * TT;
  {
    int tok0 = __builtin_amdgcn_readfirstlane(tokp[0]);
    xbuf[u] = xgtab[(size_t)tok0 * 1024 + u];
  }
  __syncthreads();

  const unsigned int* hpu = (const unsigned int*)hpak;
  const int hoff = 32 * q + (lane & 31);     // lanes l, l+32 same addr -> free 2-way
  unsigned int hsel = hpu[hoff];             // h pairs 32q+lane' for this quarter

  int toff = 0;
#pragma unroll 1
  for (int t = 0; t < TT; t++) {
    // prefetch next step's x-gate element (coalesced 2B/lane; hidden by worker phase)
    int tk = __builtin_amdgcn_readfirstlane(tokp[(t + 1 < TT) ? t + 1 : TT - 1]);
    f16 xn = xgtab[(size_t)tk * 1024 + u];

    float a0 = 0.f, a1 = 0.f, a2 = 0.f, a3 = 0.f;
    // reg segment: 1 readlane feeds 4 fdot2
#pragma unroll
    for (int i = 0; i < QP; i++) {
      unsigned int hs = (unsigned int)__builtin_amdgcn_readlane((int)hsel, i);
      a0 = fdot2u(w4[i].x, hs, a0);
      a1 = fdot2u(w4[i].y, hs, a1);
      a2 = fdot2u(w4[i].z, hs, a2);
      a3 = fdot2u(w4[i].w, hs, a3);
    }
    // LDS segment, rotated so LICM can't hoist the reads
#pragma unroll
    for (int j = 0; j < LJ; j++) {
      int je = j + toff; if (je >= LJ) je -= LJ;
      uint4 w = lw4[je * 1024 + u];
      unsigned int hs = (unsigned int)__builtin_amdgcn_readlane((int)hsel, QP + je);
      a0 = fdot2u(w.x, hs, a0);
      a1 = fdot2u(w.y, hs, a1);
      a2 = fdot2u(w.z, hs, a2);
      a3 = fdot2u(w.w, hs, a3);
    }

    if (q > 0) {
      *(float4*)&part[((q - 1) * 256 + r) * 4] = make_float4(a0, a1, a2, a3);
    }
    __syncthreads();
    if (q == 0) {
      float4 p1 = *(const float4*)&part[(0 * 256 + r) * 4];
      float4 p2 = *(const float4*)&part[(1 * 256 + r) * 4];
      float4 p3 = *(const float4*)&part[(2 * 256 + r) * 4];
      float gi = a0 + p1.x + p2.x + p3.x + (float)xbuf[r];
      float gf = a1 + p1.y + p2.y + p3.y + (float)xbuf[NHID + r];
      float gg = a2 + p1.z + p2.z + p3.z + (float)xbuf[2 * NHID + r];
      float go = a3 + p1.w + p2.w + p3.w + (float)xbuf[3 * NHID + r];
      float ig = sigm(gi), fg = sigm(gf), gt = tanh_(gg), og = sigm(go);
      c = fg * c + ig * gt;
      h = og * tanh_(c);
      pool += (t < L) ? h : 0.f;
      hpak[r] = (f16)h;
    }
    __syncthreads();
    hsel = hpu[hoff];      // h(t) for next step
    xbuf[u] = xn;          // x-gates for step t+1 (consumed after next barrier1)
    toff++; if (toff == LJ) toff = 0;
  }

  if (q == 0) {
    feat[b * NHID + r] = pool / (float)L;
    out_hx[b * NHID + r] = h;
    out_cx[b * NHID + r] = c;
  }
}

// ------------------------------------------------------------- k3: head (fp32)
__global__ __launch_bounds__(256) void k3_head(const float* __restrict__ feat,
    const float* __restrict__ rfc1_w, const float* __restrict__ rfc1_b,
    const float* __restrict__ rbn_g, const float* __restrict__ rbn_b,
    const float* __restrict__ rbn_rm, const float* __restrict__ rbn_rv,
    const float* __restrict__ rfc2_w, const float* __restrict__ rfc2_b,
    const float* __restrict__ fc1_w, const float* __restrict__ fc1_b,
    const float* __restrict__ bn1_g, const float* __restrict__ bn1_b,
    const float* __restrict__ bn1_rm, const float* __restrict__ bn1_rv,
    const float* __restrict__ fc2_w, const float* __restrict__ fc2_b,
    float* __restrict__ logp) {
  __shared__ float f[256];
  __shared__ float f2[256];
  __shared__ float res[16];
  __shared__ float fcv[96];
  const int b = blockIdx.x, tid = threadIdx.x;
  const int wv = tid >> 6, lane = tid & 63;
  f[tid] = feat[b * 256 + tid];
  __syncthreads();
  for (int r = wv; r < NRES; r += 4) {
    float p = 0.f;
#pragma unroll
    for (int j0 = 0; j0 < 4; j0++) {
      int j = lane * 4 + j0;
      p += fmaxf(f[j], 0.f) * rfc1_w[r * 256 + j];
    }
    for (int off = 32; off > 0; off >>= 1) p += __shfl_down(p, off);
    if (lane == 0) {
      float x = p + rfc1_b[r];
      x = fmaxf(x, 0.f);
      x = (x - rbn_rm[r]) * rsqrtf(rbn_rv[r] + EPSV) * rbn_g[r] + rbn_b[r];
      res[r] = x;
    }
  }
  __syncthreads();
  {
    float s = rfc2_b[tid];
#pragma unroll
    for (int r = 0; r < NRES; r++) s += res[r] * rfc2_w[tid * NRES + r];
    f2[tid] = f[tid] + s;
  }
  __syncthreads();
  for (int o = wv; o < NFC1; o += 4) {
    float p = 0.f;
#pragma unroll
    for (int j0 = 0; j0 < 4; j0++) {
      int j = lane * 4 + j0;
      p += f2[j] * fc1_w[o * 256 + j];
    }
    for (int off = 32; off > 0; off >>= 1) p += __shfl_down(p, off);
    if (lane == 0) {
      float x = p + fc1_b[o];
      x = (x - bn1_rm[o]) * rsqrtf(bn1_rv[o] + EPSV) * bn1_g[o] + bn1_b[o];
      x = fmaxf(x, 0.01f * x);
      fcv[o] = x;
    }
  }
  __syncthreads();
  if (tid == 0) {
    float l0 = fc2_b[0], l1 = fc2_b[1];
    for (int o2 = 0; o2 < NFC1; o2++) {
      l0 += fcv[o2] * fc2_w[o2];
      l1 += fcv[o2] * fc2_w[NFC1 + o2];
    }
    float mx = fmaxf(l0, l1);
    float lse = mx + __logf(__expf(l0 - mx) + __expf(l1 - mx));
    logp[b * 2 + 0] = l0 - lse;
    logp[b * 2 + 1] = l1 - lse;
  }
}

// ---------------------------------------------------------------------------
extern "C" void kernel_launch(void* const* d_in, const int* in_sizes, int n_in,
                              void* d_out, int out_size, void* d_ws, size_t ws_size,
                              hipStream_t stream) {
  const int*   input  = (const int*)  d_in[0];
  const float* hx     = (const float*)d_in[1];
  const float* cx     = (const float*)d_in[2];
  const int*   seqlen = (const int*)  d_in[3];
  const float* emb_w  = (const float*)d_in[4];
  const float* W_ih   = (const float*)d_in[5];
  const float* W_hh   = (const float*)d_in[6];
  const float* b_ih   = (const float*)d_in[7];
  const float* b_hh   = (const float*)d_in[8];
  const float* rfc1_w = (const float*)d_in[9];
  const float* rfc1_b = (const float*)d_in[10];
  const float* rbn_g  = (const float*)d_in[11];
  const float* rbn_b  = (const float*)d_in[12];
  const float* rbn_rm = (const float*)d_in[13];
  const float* rbn_rv = (const float*)d_in[14];
  const float* rfc2_w = (const float*)d_in[15];
  const float* rfc2_b = (const float*)d_in[16];
  const float* fc1_w  = (const float*)d_in[17];
  const float* fc1_b  = (const float*)d_in[18];
  const float* bn1_g  = (const float*)d_in[19];
  const float* bn1_b  = (const float*)d_in[20];
  const float* bn1_rm = (const float*)d_in[21];
  const float* bn1_rv = (const float*)d_in[22];
  const float* fc2_w  = (const float*)d_in[23];
  const float* fc2_b  = (const float*)d_in[24];

  char* ws = (char*)d_ws;
  f16*   emb16 = (f16*)(ws);                 // 25,731,584 B (dead after k1)
  f16*   wih16 = (f16*)(ws + 25731584);      //    524,288 B
  float* bias  = (float*)(ws + 26255872);    //      4,096 B
  f16*   xgtab = (f16*)(ws + 26259968);      // 102,926,336 B
  float* feat  = (float*)(ws + 129186304);   //     65,536 B

  // packed W_hh (overlays dead emb16 region; k0b runs after k1)
  unsigned int* wregq = (unsigned int*)(ws);            // 23*1024*16 = 376,832 B
  unsigned int* wldsq = (unsigned int*)(ws + 376832);   //  9*1024*16 = 147,456 B

  float* out = (float*)d_out;   // [0,128): logp, [128,16512): hx_f, [16512,32896): cx_f

  k0_convert<<<dim3(NTOKEN), 256, 0, stream>>>(emb_w, W_ih, b_ih, b_hh, emb16, wih16, bias);
  k1_gemm<<<dim3((NTOKEN + 63) / 64, 4), 256, 0, stream>>>(emb16, wih16, bias, xgtab);
  k0b_pack<<<dim3(1024), 128, 0, stream>>>(W_hh, wregq, wldsq);
  k2_rnn<<<dim3(BB), 1024, 0, stream>>>(input, hx, cx, seqlen, (const uint4*)wregq,
                                        (const uint4*)wldsq, xgtab, feat,
                                        out + 128, out + 128 + BB * NHID);
  k3_head<<<dim3(BB), 256, 0, stream>>>(feat, rfc1_w, rfc1_b, rbn_g, rbn_b, rbn_rm, rbn_rv,
                                        rfc2_w, rfc2_b, fc1_w, fc1_b, bn1_g, bn1_b, bn1_rm,
                                        bn1_rv, fc2_w, fc2_b, out);
}

// Round 7
// 4241.312 us; speedup vs baseline: 1.6416x; 1.0268x over previous
//
#include <hip/hip_runtime.h>
#include <cstdint>

// ---------------------------------------------------------------------------
// RNNres: emb -> LSTM(T=2048,B=64,NHID=256) -> ragged mean pool -> ResNet head
// Round-7 k2 = round-6 structure + anti-rematerialization pinning.
//   r3-r6 lesson: the allocator never SPILLS the weight array, it REMATS it
//   (loop-invariant loads are re-issuable), so VGPR_Count kept landing at
//   64-128 with the weights re-read from L2 every step (~4 ms plateau).
//   Fix: empty `asm volatile("" : "+v")` on every loaded weight word makes the
//   values non-rematerializable (asm results can't be recomputed), and
//   amdgpu_waves_per_eu(4,4) sets the register target to the LDS-capped
//   occupancy (162KB LDS -> 1 WG/CU = 4 waves/EU -> 128 VGPR budget).
//   Thread u: hidden unit r=u&255, K-quarter q=u>>8; owns gate rows
//   {r, r+256, r+512, r+768}; 23 uint4 in regs + 9 uint4 via rotated LDS;
//   1 readlane feeds 4 fdot2; q=0 combines partials + activations.
// ---------------------------------------------------------------------------

#define NTOKEN 50257
#define NINP 256
#define NHID 256
#define BB 64
#define TT 2048
#define NRES 10
#define NFC1 85
#define EPSV 1e-5f

#define QP 23   // reg-resident uint4 weight groups per thread (92 words)
#define LJ 9    // LDS-resident uint4 weight groups per thread (36 words)

typedef _Float16 f16;
typedef _Float16 f16x2 __attribute__((ext_vector_type(2)));
typedef _Float16 f16x8 __attribute__((ext_vector_type(8)));
typedef float f32x4 __attribute__((ext_vector_type(4)));

static __device__ __forceinline__ float sigm(float x) { return 1.0f / (1.0f + __expf(-x)); }
static __device__ __forceinline__ float tanh_(float x) {
  float ax = fabsf(x);
  float e = __expf(-2.0f * ax);
  float t = (1.0f - e) / (1.0f + e);
  return x < 0.0f ? -t : t;
}

static __device__ __forceinline__ float fdot2u(unsigned int a, unsigned int b, float c) {
#if __has_builtin(__builtin_amdgcn_fdot2)
  return __builtin_amdgcn_fdot2(__builtin_bit_cast(f16x2, a), __builtin_bit_cast(f16x2, b), c, false);
#else
  f16x2 av = __builtin_bit_cast(f16x2, a), bv = __builtin_bit_cast(f16x2, b);
  return c + (float)av[0] * (float)bv[0] + (float)av[1] * (float)bv[1];
#endif
}

// ---------------------------------------------------------------- k0: convert
__global__ void k0_convert(const float* __restrict__ emb_w, const float* __restrict__ W_ih,
                           const float* __restrict__ b_ih, const float* __restrict__ b_hh,
                           f16* __restrict__ emb16, f16* __restrict__ wih16,
                           float* __restrict__ bias) {
  int64_t i = (int64_t)blockIdx.x * blockDim.x + threadIdx.x;
  if (i < (int64_t)NTOKEN * NINP) emb16[i] = (f16)emb_w[i];
  if (i < 4 * NHID * NINP) wih16[i] = (f16)W_ih[i];
  if (i < 4 * NHID) bias[i] = b_ih[i] + b_hh[i];
}

// ------------------------------------------------- k1: gate-table f16 GEMM
__global__ __launch_bounds__(256) void k1_gemm(const f16* __restrict__ emb16,
                                               const f16* __restrict__ wih16,
                                               const float* __restrict__ bias,
                                               f16* __restrict__ xgtab) {
  __shared__ __align__(16) f16 a_lds[64][40];
  __shared__ __align__(16) f16 b_lds[256][40];
  const int mt = blockIdx.x;
  const int nt0 = blockIdx.y * 256;
  const int tid = threadIdx.x;
  const int lane = tid & 63;
  const int w = tid >> 6;
  const int quad = lane >> 4;
  const int l16 = lane & 15;

  f32x4 acc[16];
#pragma unroll
  for (int i = 0; i < 16; i++) acc[i] = (f32x4){0.f, 0.f, 0.f, 0.f};

  const int ar = tid >> 2;
  int av = mt * 64 + ar;
  if (av > NTOKEN - 1) av = NTOKEN - 1;
  const int ac = (tid & 3) * 8;

  for (int kb = 0; kb < 256; kb += 32) {
    *(uint4*)&a_lds[ar][ac] = *(const uint4*)&emb16[av * 256 + kb + ac];
    {
      const uint4* bs = (const uint4*)&wih16[(nt0 + tid) * 256 + kb];
      uint4* bd = (uint4*)&b_lds[tid][0];
      bd[0] = bs[0]; bd[1] = bs[1]; bd[2] = bs[2]; bd[3] = bs[3];
    }
    __syncthreads();
    f16x8 af = *(const f16x8*)&a_lds[w * 16 + l16][quad * 8];
#pragma unroll
    for (int nt = 0; nt < 16; nt++) {
      f16x8 bf = *(const f16x8*)&b_lds[nt * 16 + l16][quad * 8];
      acc[nt] = __builtin_amdgcn_mfma_f32_16x16x32_f16(af, bf, acc[nt], 0, 0, 0);
    }
    __syncthreads();
  }
#pragma unroll
  for (int nt = 0; nt < 16; nt++) {
#pragma unroll
    for (int rg = 0; rg < 4; rg++) {
      int v = mt * 64 + w * 16 + quad * 4 + rg;
      if (v < NTOKEN) {
        int n = nt0 + nt * 16 + l16;
        xgtab[v * 1024 + n] = (f16)(acc[nt][rg] + bias[n]);
      }
    }
  }
}

// --------------------------------------------- k0b: pack W_hh for k2
// For k2-thread u (r=u&255, q=u>>8): group pi holds pair p = 32q + pi for the
// 4 gate rows {r, r+256, r+512, r+768} as .x/.y/.z/.w.
__global__ __launch_bounds__(128) void k0b_pack(const float* __restrict__ Whh,
                                                unsigned int* __restrict__ wregq,
                                                unsigned int* __restrict__ wldsq) {
  const int R = blockIdx.x;        // gate row 0..1023
  const int p = threadIdx.x;       // pair 0..127
  float2 a = *(const float2*)&Whh[R * 256 + 2 * p];
  f16x2 pk; pk[0] = (f16)a.x; pk[1] = (f16)a.y;
  unsigned int uu = __builtin_bit_cast(unsigned int, pk);
  int u = (R & 255) + 256 * (p >> 5);   // k2 thread that consumes this pair
  int ri = R >> 8;                      // gate index (i,f,g,o)
  int pp = p & 31;                      // pair index within the quarter
  if (pp < QP) wregq[(pp * 1024 + u) * 4 + ri] = uu;
  else         wldsq[((pp - QP) * 1024 + u) * 4 + ri] = uu;
}

// ------------------------------------------------------- k2: LSTM recurrence
// One WG per batch element, 1024 thr (16 waves; LDS caps at 1 WG/CU = 4 w/EU).
__global__ __launch_bounds__(1024)
__attribute__((amdgpu_waves_per_eu(4, 4)))
void k2_rnn(
    const int* __restrict__ input, const float* __restrict__ hx0,
    const float* __restrict__ cx0, const int* __restrict__ seq_len,
    const uint4* __restrict__ wregq, const uint4* __restrict__ wldsq,
    const f16* __restrict__ xgtab,
    float* __restrict__ feat, float* __restrict__ out_hx, float* __restrict__ out_cx) {
  __shared__ uint4 lw4[LJ * 1024];            // 147456 B
  __shared__ float part[3 * 256 * 4];         //  12288 B  (quarters 1..3 partials)
  __shared__ f16 xbuf[1024];                  //   2048 B  (current step x-gates)
  __shared__ __align__(8) f16 hpak[NHID];     //    512 B  -> total 162304 B

  const int b = blockIdx.x;
  const int u = threadIdx.x;
  const int lane = u & 63;
  const int r = u & 255;        // hidden unit
  const int q = u >> 8;         // K-quarter (wave-uniform)

  // resident weights: 23 uint4 (pairs 32q .. 32q+22, gates i,f,g,o)
  uint4 w4[QP];
#pragma unroll
  for (int i = 0; i < QP; i++) w4[i] = wregq[i * 1024 + u];
  // pin: empty asm makes each word non-rematerializable -> allocator must
  // keep it live (or spill, which WRITE_SIZE would expose). This is the
  // anti-remat fix for the r3-r6 "reload weights from L2 every step" plateau.
#pragma unroll
  for (int i = 0; i < QP; i++) {
    asm volatile("" : "+v"(w4[i].x), "+v"(w4[i].y), "+v"(w4[i].z), "+v"(w4[i].w));
  }

  // LDS weights: 9 uint4 (pairs 32q+23 .. 32q+31)
#pragma unroll
  for (int j = 0; j < LJ; j++) lw4[j * 1024 + u] = wldsq[j * 1024 + u];

  float c = 0.f, pool = 0.f, h = 0.f;
  if (u < NHID) {
    hpak[u] = (f16)hx0[b * NHID + u];
    c = cx0[b * NHID + u];
  }
  const int L = seq_len[b];
  const int* tokp = input + b * TT;
  {
    int tok0 = __builtin_amdgcn_readfirstlane(tokp[0]);
    xbuf[u] = xgtab[(size_t)tok0 * 1024 + u];
  }
  __syncthreads();

  const unsigned int* hpu = (const unsigned int*)hpak;
  const int hoff = 32 * q + (lane & 31);     // lanes l, l+32 same addr -> free 2-way
  unsigned int hsel = hpu[hoff];             // h pairs 32q+lane' for this quarter

  int toff = 0;
#pragma unroll 1
  for (int t = 0; t < TT; t++) {
    // prefetch next step's x-gate element (coalesced 2B/lane; hidden by worker phase)
    int tk = __builtin_amdgcn_readfirstlane(tokp[(t + 1 < TT) ? t + 1 : TT - 1]);
    f16 xn = xgtab[(size_t)tk * 1024 + u];

    float a0 = 0.f, a1 = 0.f, a2 = 0.f, a3 = 0.f;
    // reg segment: 1 readlane feeds 4 fdot2
#pragma unroll
    for (int i = 0; i < QP; i++) {
      unsigned int hs = (unsigned int)__builtin_amdgcn_readlane((int)hsel, i);
      a0 = fdot2u(w4[i].x, hs, a0);
      a1 = fdot2u(w4[i].y, hs, a1);
      a2 = fdot2u(w4[i].z, hs, a2);
      a3 = fdot2u(w4[i].w, hs, a3);
    }
    // LDS segment, rotated so LICM can't hoist the reads
#pragma unroll
    for (int j = 0; j < LJ; j++) {
      int je = j + toff; if (je >= LJ) je -= LJ;
      uint4 w = lw4[je * 1024 + u];
      unsigned int hs = (unsigned int)__builtin_amdgcn_readlane((int)hsel, QP + je);
      a0 = fdot2u(w.x, hs, a0);
      a1 = fdot2u(w.y, hs, a1);
      a2 = fdot2u(w.z, hs, a2);
      a3 = fdot2u(w.w, hs, a3);
    }

    if (q > 0) {
      *(float4*)&part[((q - 1) * 256 + r) * 4] = make_float4(a0, a1, a2, a3);
    }
    __syncthreads();
    if (q == 0) {
      float4 p1 = *(const float4*)&part[(0 * 256 + r) * 4];
      float4 p2 = *(const float4*)&part[(1 * 256 + r) * 4];
      float4 p3 = *(const float4*)&part[(2 * 256 + r) * 4];
      float gi = a0 + p1.x + p2.x + p3.x + (float)xbuf[r];
      float gf = a1 + p1.y + p2.y + p3.y + (float)xbuf[NHID + r];
      float gg = a2 + p1.z + p2.z + p3.z + (float)xbuf[2 * NHID + r];
      float go = a3 + p1.w + p2.w + p3.w + (float)xbuf[3 * NHID + r];
      float ig = sigm(gi), fg = sigm(gf), gt = tanh_(gg), og = sigm(go);
      c = fg * c + ig * gt;
      h = og * tanh_(c);
      pool += (t < L) ? h : 0.f;
      hpak[r] = (f16)h;
    }
    __syncthreads();
    hsel = hpu[hoff];      // h(t) for next step
    xbuf[u] = xn;          // x-gates for step t+1 (consumed after next barrier1)
    toff++; if (toff == LJ) toff = 0;
  }

  if (q == 0) {
    feat[b * NHID + r] = pool / (float)L;
    out_hx[b * NHID + r] = h;
    out_cx[b * NHID + r] = c;
  }
}

// ------------------------------------------------------------- k3: head (fp32)
__global__ __launch_bounds__(256) void k3_head(const float* __restrict__ feat,
    const float* __restrict__ rfc1_w, const float* __restrict__ rfc1_b,
    const float* __restrict__ rbn_g, const float* __restrict__ rbn_b,
    const float* __restrict__ rbn_rm, const float* __restrict__ rbn_rv,
    const float* __restrict__ rfc2_w, const float* __restrict__ rfc2_b,
    const float* __restrict__ fc1_w, const float* __restrict__ fc1_b,
    const float* __restrict__ bn1_g, const float* __restrict__ bn1_b,
    const float* __restrict__ bn1_rm, const float* __restrict__ bn1_rv,
    const float* __restrict__ fc2_w, const float* __restrict__ fc2_b,
    float* __restrict__ logp) {
  __shared__ float f[256];
  __shared__ float f2[256];
  __shared__ float res[16];
  __shared__ float fcv[96];
  const int b = blockIdx.x, tid = threadIdx.x;
  const int wv = tid >> 6, lane = tid & 63;
  f[tid] = feat[b * 256 + tid];
  __syncthreads();
  for (int r = wv; r < NRES; r += 4) {
    float p = 0.f;
#pragma unroll
    for (int j0 = 0; j0 < 4; j0++) {
      int j = lane * 4 + j0;
      p += fmaxf(f[j], 0.f) * rfc1_w[r * 256 + j];
    }
    for (int off = 32; off > 0; off >>= 1) p += __shfl_down(p, off);
    if (lane == 0) {
      float x = p + rfc1_b[r];
      x = fmaxf(x, 0.f);
      x = (x - rbn_rm[r]) * rsqrtf(rbn_rv[r] + EPSV) * rbn_g[r] + rbn_b[r];
      res[r] = x;
    }
  }
  __syncthreads();
  {
    float s = rfc2_b[tid];
#pragma unroll
    for (int r = 0; r < NRES; r++) s += res[r] * rfc2_w[tid * NRES + r];
    f2[tid] = f[tid] + s;
  }
  __syncthreads();
  for (int o = wv; o < NFC1; o += 4) {
    float p = 0.f;
#pragma unroll
    for (int j0 = 0; j0 < 4; j0++) {
      int j = lane * 4 + j0;
      p += f2[j] * fc1_w[o * 256 + j];
    }
    for (int off = 32; off > 0; off >>= 1) p += __shfl_down(p, off);
    if (lane == 0) {
      float x = p + fc1_b[o];
      x = (x - bn1_rm[o]) * rsqrtf(bn1_rv[o] + EPSV) * bn1_g[o] + bn1_b[o];
      x = fmaxf(x, 0.01f * x);
      fcv[o] = x;
    }
  }
  __syncthreads();
  if (tid == 0) {
    float l0 = fc2_b[0], l1 = fc2_b[1];
    for (int o2 = 0; o2 < NFC1; o2++) {
      l0 += fcv[o2] * fc2_w[o2];
      l1 += fcv[o2] * fc2_w[NFC1 + o2];
    }
    float mx = fmaxf(l0, l1);
    float lse = mx + __logf(__expf(l0 - mx) + __expf(l1 - mx));
    logp[b * 2 + 0] = l0 - lse;
    logp[b * 2 + 1] = l1 - lse;
  }
}

// ---------------------------------------------------------------------------
extern "C" void kernel_launch(void* const* d_in, const int* in_sizes, int n_in,
                              void* d_out, int out_size, void* d_ws, size_t ws_size,
                              hipStream_t stream) {
  const int*   input  = (const int*)  d_in[0];
  const float* hx     = (const float*)d_in[1];
  const float* cx     = (const float*)d_in[2];
  const int*   seqlen = (const int*)  d_in[3];
  const float* emb_w  = (const float*)d_in[4];
  const float* W_ih   = (const float*)d_in[5];
  const float* W_hh   = (const float*)d_in[6];
  const float* b_ih   = (const float*)d_in[7];
  const float* b_hh   = (const float*)d_in[8];
  const float* rfc1_w = (const float*)d_in[9];
  const float* rfc1_b = (const float*)d_in[10];
  const float* rbn_g  = (const float*)d_in[11];
  const float* rbn_b  = (const float*)d_in[12];
  const float* rbn_rm = (const float*)d_in[13];
  const float* rbn_rv = (const float*)d_in[14];
  const float* rfc2_w = (const float*)d_in[15];
  const float* rfc2_b = (const float*)d_in[16];
  const float* fc1_w  = (const float*)d_in[17];
  const float* fc1_b  = (const float*)d_in[18];
  const float* bn1_g  = (const float*)d_in[19];
  const float* bn1_b  = (const float*)d_in[20];
  const float* bn1_rm = (const float*)d_in[21];
  const float* bn1_rv = (const float*)d_in[22];
  const float* fc2_w  = (const float*)d_in[23];
  const float* fc2_b  = (const float*)d_in[24];

  char* ws = (char*)d_ws;
  f16*   emb16 = (f16*)(ws);                 // 25,731,584 B (dead after k1)
  f16*   wih16 = (f16*)(ws + 25731584);      //    524,288 B
  float* bias  = (float*)(ws + 26255872);    //      4,096 B
  f16*   xgtab = (f16*)(ws + 26259968);      // 102,926,336 B
  float* feat  = (float*)(ws + 129186304);   //     65,536 B

  // packed W_hh (overlays dead emb16 region; k0b runs after k1)
  unsigned int* wregq = (unsigned int*)(ws);            // 23*1024*16 = 376,832 B
  unsigned int* wldsq = (unsigned int*)(ws + 376832);   //  9*1024*16 = 147,456 B

  float* out = (float*)d_out;   // [0,128): logp, [128,16512): hx_f, [16512,32896): cx_f

  k0_convert<<<dim3(NTOKEN), 256, 0, stream>>>(emb_w, W_ih, b_ih, b_hh, emb16, wih16, bias);
  k1_gemm<<<dim3((NTOKEN + 63) / 64, 4), 256, 0, stream>>>(emb16, wih16, bias, xgtab);
  k0b_pack<<<dim3(1024), 128, 0, stream>>>(W_hh, wregq, wldsq);
  k2_rnn<<<dim3(BB), 1024, 0, stream>>>(input, hx, cx, seqlen, (const uint4*)wregq,
                                        (const uint4*)wldsq, xgtab, feat,
                                        out + 128, out + 128 + BB * NHID);
  k3_head<<<dim3(BB), 256, 0, stream>>>(feat, rfc1_w, rfc1_b, rbn_g, rbn_b, rbn_rm, rbn_rv,
                                        rfc2_w, rfc2_b, fc1_w, fc1_b, bn1_g, bn1_b, bn1_rm,
                                        bn1_rv, fc2_w, fc2_b, out);
}